// Round 1
// baseline (524.440 us; speedup 1.0000x reference)
//
#include <hip/hip_runtime.h>
#include <stdint.h>

// Problem constants (from reference):
//   VOC_SIZE = 1,000,000, EMBED_DIM = 64, N_UPD = 262,144, B*L = 819,200
// Inputs:
//   d_in[0]: kernel      float32 [1,000,000 * 64]   (NOT mutated in this version)
//   d_in[1]: indices     int32   [262,144]
//   d_in[2]: emb_update  float32 [262,144 * 64]
//   d_in[3]: qs          int32   [819,200]
// Output: float32 [819,200 * 64]
//
// Strategy: never write d_in[0] (avoids the harness's timed 256 MB table
// restore). Updates are accumulated into a sparse delta in the workspace,
// keyed by an open-addressing hash table; the gather fuses table + delta.

#define EMBED_DIM 64
#define NSLOT_LOG 20
#define NSLOT (1u << NSLOT_LOG)     // 1,048,576 slots; load factor ~22%
#define HMASK (NSLOT - 1u)

__device__ __forceinline__ unsigned hash_row(unsigned row) {
    // Knuth multiplicative hash, take high NSLOT_LOG bits.
    return (row * 2654435761u) >> (32 - NSLOT_LOG);
}

// ---- Phase 0: zero the hash-key array (4 MB). Self-contained: we do not
// rely on the harness zeroing the workspace between iterations.
__global__ void zero_keys_kernel(uint4* __restrict__ keys4, int n4) {
    int t = blockIdx.x * blockDim.x + threadIdx.x;
    if (t < n4) keys4[t] = make_uint4(0u, 0u, 0u, 0u);
}

// ---- Phase 1: one thread per update row. Claim a hash slot for the row
// (key = row+1, 0 = empty), record it, and zero the slot's 256 B delta row.
// Duplicate rows zero the same slot concurrently with identical zeros: benign.
__global__ void build_hash_kernel(const int* __restrict__ indices,
                                  unsigned* __restrict__ keys,
                                  int* __restrict__ slot_of,
                                  float4* __restrict__ delta,
                                  int n_upd) {
    int i = blockIdx.x * blockDim.x + threadIdx.x;
    if (i >= n_upd) return;
    unsigned row = (unsigned)indices[i];
    unsigned key = row + 1u;
    unsigned p = hash_row(row);
    for (;;) {
        unsigned old = atomicCAS(&keys[p], 0u, key);
        if (old == 0u || old == key) break;   // claimed it, or co-owner
        p = (p + 1u) & HMASK;                 // linear probe
    }
    slot_of[i] = (int)p;
    float4 z = make_float4(0.f, 0.f, 0.f, 0.f);
    float4* drow = delta + ((size_t)p << 4);  // 16 float4 per row
#pragma unroll
    for (int c = 0; c < 16; ++c) drow[c] = z;
}

// ---- Phase 2: one thread per update element (64 per row), coalesced
// atomicAdd into the delta row. Footprint ~59 MB -> L2/L3-resident RMW.
__global__ void accumulate_kernel(const float* __restrict__ upd,
                                  const int* __restrict__ slot_of,
                                  float* __restrict__ delta,
                                  int total /* n_upd * 64 */) {
    int tid = blockIdx.x * blockDim.x + threadIdx.x;
    if (tid >= total) return;
    int i = tid >> 6;   // update row
    int d = tid & 63;   // column
    int slot = slot_of[i];   // broadcast across the 64 lanes of a row
    atomicAdd(&delta[((size_t)slot << 6) + d], upd[tid]);
}

// ---- Phase 3: gather, fusing the delta add. 16 threads per query row,
// float4 per thread. Probe loads hit the same addresses for all 16 lanes
// of a row -> L1 broadcast.
__global__ void gather_fused_kernel(const float4* __restrict__ table,
                                    const int* __restrict__ qs,
                                    const unsigned* __restrict__ keys,
                                    const float4* __restrict__ delta,
                                    float4* __restrict__ out,
                                    int total /* n_q * 16 */) {
    int tid = blockIdx.x * blockDim.x + threadIdx.x;
    if (tid >= total) return;
    int r = tid >> 4;   // query index
    int c = tid & 15;   // float4 chunk within row
    unsigned row = (unsigned)qs[r];
    unsigned key = row + 1u;
    unsigned p = hash_row(row);
    int slot = -1;
    for (;;) {
        unsigned k = keys[p];
        if (k == key) { slot = (int)p; break; }  // row was updated
        if (k == 0u) break;                      // row untouched
        p = (p + 1u) & HMASK;
    }
    float4 v = table[((size_t)row << 4) + c];
    if (slot >= 0) {
        float4 dv = delta[((size_t)slot << 4) + c];
        v.x += dv.x; v.y += dv.y; v.z += dv.z; v.w += dv.w;
    }
    out[tid] = v;
}

// ---------------- fallback path (original in-place algorithm) -------------
__global__ void scatter_add_kernel(float* __restrict__ table,
                                   const int* __restrict__ indices,
                                   const float* __restrict__ upd,
                                   int total) {
    int tid = blockIdx.x * blockDim.x + threadIdx.x;
    if (tid >= total) return;
    int i = tid >> 6;
    int d = tid & 63;
    int row = indices[i];
    atomicAdd(&table[(size_t)row * EMBED_DIM + d], upd[tid]);
}

__global__ void gather_kernel(const float4* __restrict__ table,
                              const int* __restrict__ qs,
                              float4* __restrict__ out,
                              int total) {
    int tid = blockIdx.x * blockDim.x + threadIdx.x;
    if (tid >= total) return;
    int r = tid >> 4;
    int c = tid & 15;
    int q = qs[r];
    out[tid] = table[q * 16 + c];
}
// --------------------------------------------------------------------------

extern "C" void kernel_launch(void* const* d_in, const int* in_sizes, int n_in,
                              void* d_out, int out_size, void* d_ws, size_t ws_size,
                              hipStream_t stream) {
    const float* table = (const float*)d_in[0];
    const int* indices = (const int*)d_in[1];
    const float* upd = (const float*)d_in[2];
    const int* qs = (const int*)d_in[3];
    float* out = (float*)d_out;

    const int n_upd = in_sizes[1];                  // 262,144
    const int n_q = in_sizes[3];                    // 819,200
    const int block = 256;

    // Workspace layout (all offsets 16B-aligned):
    //   [0, 4 MB)            hash keys   (NSLOT * u32)
    //   [4 MB, 4 MB + n_upd*4)  slot_of  (per-update slot)
    //   [8 MB, 8 MB + NSLOT*256)  delta  (NSLOT rows * 64 f32)
    const size_t keys_bytes  = (size_t)NSLOT * 4;                 // 4 MB
    const size_t delta_off   = 8u * 1024u * 1024u;                // 8 MB
    const size_t need = delta_off + (size_t)NSLOT * EMBED_DIM * 4; // ~277 MB

    if (ws_size >= need) {
        unsigned* keys = (unsigned*)d_ws;
        int* slot_of   = (int*)((char*)d_ws + keys_bytes);
        float* delta   = (float*)((char*)d_ws + delta_off);

        const int nkeys4 = (int)(NSLOT / 4);
        zero_keys_kernel<<<(nkeys4 + block - 1) / block, block, 0, stream>>>(
            (uint4*)keys, nkeys4);

        build_hash_kernel<<<(n_upd + block - 1) / block, block, 0, stream>>>(
            indices, keys, slot_of, (float4*)delta, n_upd);

        const int acc_total = n_upd * EMBED_DIM;    // 16,777,216
        accumulate_kernel<<<(acc_total + block - 1) / block, block, 0, stream>>>(
            upd, slot_of, delta, acc_total);

        const int gat_total = n_q * (EMBED_DIM / 4); // 13,107,200
        gather_fused_kernel<<<(gat_total + block - 1) / block, block, 0, stream>>>(
            (const float4*)table, qs, keys, (const float4*)delta,
            (float4*)out, gat_total);
    } else {
        // Fallback: in-place scatter + gather (mutates d_in[0]).
        float* mtable = (float*)d_in[0];
        const int scatter_total = n_upd * EMBED_DIM;
        const int gather_total = n_q * (EMBED_DIM / 4);
        scatter_add_kernel<<<(scatter_total + block - 1) / block, block, 0, stream>>>(
            mtable, indices, upd, scatter_total);
        gather_kernel<<<(gather_total + block - 1) / block, block, 0, stream>>>(
            (const float4*)mtable, qs, (float4*)out, gather_total);
    }
}

// Round 3
// 470.538 us; speedup vs baseline: 1.1146x; 1.1146x over previous
//
#include <hip/hip_runtime.h>
#include <stdint.h>

// Problem constants (from reference):
//   VOC_SIZE = 1,000,000, EMBED_DIM = 64, N_UPD = 262,144, B*L = 819,200
// Inputs:
//   d_in[0]: kernel      float32 [1,000,000 * 64]   (mutated in place; harness
//                                                    restores unconditionally)
//   d_in[1]: indices     int32   [262,144]
//   d_in[2]: emb_update  float32 [262,144 * 64]
//   d_in[3]: qs          int32   [819,200]
// Output: float32 [819,200 * 64]
//
// In-place scatter + gather, micro-optimized:
//   - unsafeAtomicAdd -> guaranteed global_atomic_add_f32 (no CAS retry loop)
//   - nontemporal load of the stream-once update matrix
//   - nontemporal store of the stream-once output (keeps L2/L3 for table rows)
// Note: __builtin_nontemporal_* requires a clang vector type, not HIP's
// float4 class -> use ext_vector_type(4).

#define EMBED_DIM 64

typedef float floatx4 __attribute__((ext_vector_type(4)));

// One thread per update element: 64 consecutive threads = one 256 B table row,
// so the wave's 64 atomics land on one contiguous row (coalesced RMW traffic).
__global__ __launch_bounds__(256) void scatter_add_kernel(
        float* __restrict__ table,
        const int* __restrict__ indices,
        const float* __restrict__ upd,
        int total /* n_upd * 64 */) {
    int tid = blockIdx.x * blockDim.x + threadIdx.x;
    if (tid >= total) return;
    int i = tid >> 6;   // update row (wave-uniform)
    int d = tid & 63;   // column
    int row = indices[i];
    float v = __builtin_nontemporal_load(&upd[tid]);
#if defined(__HIP_DEVICE_COMPILE__)
    unsafeAtomicAdd(&table[(size_t)row * EMBED_DIM + d], v);
#else
    atomicAdd(&table[(size_t)row * EMBED_DIM + d], v);
#endif
}

// One thread per output float4: 16 threads cooperate on one 256 B row.
// Table reads stay cached (duplicate queries re-hit L2/L3); output is
// streamed once -> nontemporal store to avoid evicting table lines.
__global__ __launch_bounds__(256) void gather_kernel(
        const floatx4* __restrict__ table,
        const int* __restrict__ qs,
        floatx4* __restrict__ out,
        int total /* n_q * 16 */) {
    int tid = blockIdx.x * blockDim.x + threadIdx.x;
    if (tid >= total) return;
    int r = tid >> 4;   // query index
    int c = tid & 15;   // float4 chunk within the row
    int q = qs[r];
    floatx4 v = table[(size_t)q * 16 + c];
    __builtin_nontemporal_store(v, &out[tid]);
}

extern "C" void kernel_launch(void* const* d_in, const int* in_sizes, int n_in,
                              void* d_out, int out_size, void* d_ws, size_t ws_size,
                              hipStream_t stream) {
    float* table = (float*)d_in[0];                    // mutated in place
    const int* indices = (const int*)d_in[1];
    const float* upd = (const float*)d_in[2];
    const int* qs = (const int*)d_in[3];
    float* out = (float*)d_out;

    const int n_upd = in_sizes[1];                     // 262,144
    const int n_q = in_sizes[3];                       // 819,200

    const int scatter_total = n_upd * EMBED_DIM;       // 16,777,216
    const int gather_total = n_q * (EMBED_DIM / 4);    // 13,107,200

    const int block = 256;
    scatter_add_kernel<<<(scatter_total + block - 1) / block, block, 0, stream>>>(
        table, indices, upd, scatter_total);
    gather_kernel<<<(gather_total + block - 1) / block, block, 0, stream>>>(
        (const floatx4*)table, qs, (floatx4*)out, gather_total);
}